// Round 3
// baseline (710.754 us; speedup 1.0000x reference)
//
#include <hip/hip_runtime.h>
#include <hip/hip_bf16.h>

#define DIM    16
#define BATCH  32
#define KL     4
#define NTS    512
#define NC     4
#define NPAR   16
#define DTF    (1.0f/512.0f)
#define BST    40     // bf16 L-const row stride (ushort)
#define FS     36     // f32 scratch row stride (dwords); 36*4B=144B, 16B-aligned rows

using short8  = __attribute__((ext_vector_type(8))) short;
using short4v = __attribute__((ext_vector_type(4))) short;
using f32x4   = __attribute__((ext_vector_type(4))) float;

__device__ __forceinline__ float b2f(__hip_bfloat16 x) { return __bfloat162float(x); }

__device__ __forceinline__ float ldval(const void* p, int idx, bool isf32) {
  return isf32 ? ((const float*)p)[idx]
               : __bfloat162float(((const __hip_bfloat16*)p)[idx]);
}
__device__ __forceinline__ unsigned short f2bf(float x) {   // RNE (setup/L only)
  unsigned u = __float_as_uint(x);
  unsigned r = u + 0x7FFFu + ((u >> 16) & 1u);
  return (unsigned short)(r >> 16);
}
__device__ __forceinline__ float bf2f(unsigned short h) {
  return __uint_as_float(((unsigned)h) << 16);
}
__device__ __forceinline__ short8 ldfrag(const unsigned short* p) {
  return *(const short8*)p;
}
__device__ __forceinline__ short8 negbf8(short8 a) {
  union { short8 s; unsigned u[4]; } v; v.s = a;
  #pragma unroll
  for (int q = 0; q < 4; ++q) v.u[q] ^= 0x80008000u;
  return v.s;
}
__device__ __forceinline__ f32x4 mm3(short8 Ah, short8 Al, short8 Bh, short8 Bl, f32x4 acc) {
  acc = __builtin_amdgcn_mfma_f32_16x16x32_bf16(Ah, Bh, acc, 0, 0, 0);
  acc = __builtin_amdgcn_mfma_f32_16x16x32_bf16(Al, Bh, acc, 0, 0, 0);
  acc = __builtin_amdgcn_mfma_f32_16x16x32_bf16(Ah, Bl, acc, 0, 0, 0);
  return acc;
}
// trunc hi/lo pack of 8 f32 via v_perm_b32 — bit-identical to split2 (R0-pass-verified)
__device__ __forceinline__ void pack8v(f32x4 a, f32x4 b, short8& hi, short8& lo) {
  union { short8 s; unsigned d[4]; } H, L;
  float v[8] = {a[0], a[1], a[2], a[3], b[0], b[1], b[2], b[3]};
  #pragma unroll
  for (int j = 0; j < 4; ++j) {
    unsigned ua = __float_as_uint(v[2*j]), ub = __float_as_uint(v[2*j+1]);
    H.d[j] = __builtin_amdgcn_perm(ub, ua, 0x07060302u);
    float ra = v[2*j]   - __uint_as_float(ua & 0xFFFF0000u);
    float rb = v[2*j+1] - __uint_as_float(ub & 0xFFFF0000u);
    L.d[j] = __builtin_amdgcn_perm(__float_as_uint(rb), __float_as_uint(ra), 0x07060302u);
  }
  hi = H.s; lo = L.s;
}
__device__ __forceinline__ void pack8a(const float* v, short8& hi, short8& lo) {
  union { short8 s; unsigned d[4]; } H, L;
  #pragma unroll
  for (int j = 0; j < 4; ++j) {
    unsigned ua = __float_as_uint(v[2*j]), ub = __float_as_uint(v[2*j+1]);
    H.d[j] = __builtin_amdgcn_perm(ub, ua, 0x07060302u);
    float ra = v[2*j]   - __uint_as_float(ua & 0xFFFF0000u);
    float rb = v[2*j+1] - __uint_as_float(ub & 0xFFFF0000u);
    L.d[j] = __builtin_amdgcn_perm(__float_as_uint(rb), __float_as_uint(ra), 0x07060302u);
  }
  hi = H.s; lo = L.s;
}

// R2: FULLY-FUSED single-wave chain. One wave per batch element does M, T, J and the
// update every step. All cross-layout transposes are SAME-WAVE LDS round-trips (f32
// scratch, in-order DS pipe) — ZERO barriers in the 512-step loop. All fragment
// offsets, negation patterns and update signs are verbatim from the R0-verified paths;
// f32-scratch + pack-on-read reproduces the split2 hi/lo bits exactly.
__global__ __launch_bounds__(128, 1)
void lindblad_evolve(const void* __restrict__ g_params,
                     const void* __restrict__ g_H0re, const void* __restrict__ g_H0im,
                     const void* __restrict__ g_Hcre, const void* __restrict__ g_Hcim,
                     const void* __restrict__ g_Lre,  const void* __restrict__ g_Lim,
                     const void* __restrict__ g_r0re, const void* __restrict__ g_r0im,
                     float* __restrict__ g_out)
{
  __shared__ float sG[10*256];                                        // G planes
  __shared__ __align__(16) float sU[NTS][NC];
  __shared__ __align__(16) unsigned short sLh[KL][16*BST], sLl[KL][16*BST]; // L'_k hi/lo
  __shared__ __align__(16) float sPf[16*FS];        // rho^T [re|im] f32, rows 32 wide
  __shared__ __align__(16) float sTf[KL][16*FS];    // T_k rows [Tr|Ti] f32
  __shared__ __align__(16) float sMr[16*FS], sMi[16*FS];  // M "^T-row" scratch
  __shared__ int sFlag;

  const int tid = threadIdx.x;       // 0..127 (2 waves; wave1 = setup helper only)
  const int b   = blockIdx.x;
  const int wv  = tid >> 6;
  const int ln  = tid & 63;
  const int fm  = ln & 15;
  const int fq  = ln >> 4;
  const int fOff  = fm*BST + fq*8;
  const int fOffS = fm*BST + ((fq*8 + 16) & 31);
  const int swp   = (fq*8 + 16) & 31;               // f32 swapped-window column

  // ---- input storage-dtype detection (R1/R2-verified) ----
  if (tid == 0) sFlag = 0;
  __syncthreads();
  for (int e = tid; e < 256; e += 128) {
    float v = b2f(((const __hip_bfloat16*)g_H0re)[e]);
    if (!(fabsf(v) <= 1e10f)) atomicOr(&sFlag, 1);
  }
  __syncthreads();
  const bool isf32 = (sFlag != 0);

  // ---- B-spline control pulses (128 threads: 4 passes) ----
  for (int t0 = tid; t0 < NTS; t0 += 128) {
    float kn[20];
    kn[0] = 0.f; kn[1] = 0.f; kn[2] = 0.f;
    #pragma unroll
    for (int q = 0; q < 14; ++q) kn[3 + q] = (float)q / 13.0f;
    kn[17] = 1.f; kn[18] = 1.f; kn[19] = 1.f;
    const float t = (float)t0 * DTF;
    float B[19];
    #pragma unroll
    for (int q = 0; q < 19; ++q) B[q] = (kn[q] <= t && t < kn[q+1]) ? 1.f : 0.f;
    #pragma unroll
    for (int d = 1; d <= 3; ++d) {
      #pragma unroll
      for (int q = 0; q + d < 19; ++q) {
        float ld = kn[q+d]   - kn[q];
        float rd = kn[q+d+1] - kn[q+1];
        float lv = (ld > 0.f) ? (t - kn[q])     / ld * B[q]   : 0.f;
        float rv = (rd > 0.f) ? (kn[q+d+1] - t) / rd * B[q+1] : 0.f;
        B[q] = lv + rv;
      }
    }
    #pragma unroll
    for (int c = 0; c < NC; ++c) {
      float s = 0.f;
      #pragma unroll
      for (int q = 0; q < NPAR; ++q) s += B[q] * ldval(g_params, q*NC + c, isf32);
      sU[t0][c] = s;
    }
  }

  // ---- constants staging (128 threads: 2 passes, elementwise (i,j)) ----
  for (int e = tid; e < 256; e += 128) {
    const int i = e >> 4, j = e & 15;
    const int ij = i*16 + j, ji = j*16 + i;
    float h0r = 0.5f * (ldval(g_H0re, ij, isf32) + ldval(g_H0re, ji, isf32));
    float h0i = 0.5f * (ldval(g_H0im, ij, isf32) - ldval(g_H0im, ji, isf32));
    float ldr = 0.f, ldi = 0.f;
    for (int k = 0; k < KL; ++k) {
      #pragma unroll
      for (int m = 0; m < DIM; ++m) {
        float ar = ldval(g_Lre, k*256 + m*16 + i, isf32), ai = ldval(g_Lim, k*256 + m*16 + i, isf32);
        float br = ldval(g_Lre, k*256 + m*16 + j, isf32), bi = ldval(g_Lim, k*256 + m*16 + j, isf32);
        ldr += ar*br + ai*bi;
        ldi += ar*bi - ai*br;
      }
    }
    sG[0*256 + ij] =  h0i - 0.5f*ldr;   // G0r
    sG[1*256 + ij] = -h0r - 0.5f*ldi;   // G0i
    #pragma unroll
    for (int c = 0; c < NC; ++c) {
      float hr = 0.5f * (ldval(g_Hcre, c*256 + ij, isf32) + ldval(g_Hcre, c*256 + ji, isf32));
      float hi = 0.5f * (ldval(g_Hcim, c*256 + ij, isf32) - ldval(g_Hcim, c*256 + ji, isf32));
      sG[(2 + 2*c)*256 + ij] =  hi;
      sG[(3 + 2*c)*256 + ij] = -hr;
    }
    // L': RNE hi/lo split (bf16 operand LDS, read once into registers below)
    #pragma unroll
    for (int k = 0; k < KL; ++k) {
      float lr = ldval(g_Lre, k*256 + ij, isf32);
      float li = ldval(g_Lim, k*256 + ij, isf32);
      unsigned short h;
      h = f2bf(lr); sLh[k][i*BST + j]      = h; sLl[k][i*BST + j]      = f2bf(lr - bf2f(h));
      h = f2bf(li); sLh[k][i*BST + 16 + j] = h; sLl[k][i*BST + 16 + j] = f2bf(li - bf2f(h));
    }
    // rho^T(0) in f32: sPf[j][i] = rho_re[i][j], sPf[j][16+i] = rho_im[i][j]
    sPf[j*FS + i]      = ldval(g_r0re, b*256 + ij, isf32);
    sPf[j*FS + 16 + i] = ldval(g_r0im, b*256 + ij, isf32);
  }

  __syncthreads();   // setup visible; last barrier in the kernel
  if (wv != 0) return;   // wave1 retires; wave0 runs the barrier-free loop

  // ---- per-wave preloads (all constants into registers) ----
  float G0v[8], Gcv[NC][8];
  {
    const int comp = (fq < 2) ? 0 : 1;
    const int base = (fq & 1) * 8;
    {
      const float* s0 = &sG[comp*256 + fm*16 + base];
      f32x4 va = *(const f32x4*)s0, vb = *(const f32x4*)(s0 + 4);
      #pragma unroll
      for (int q = 0; q < 4; ++q) { G0v[q] = va[q]; G0v[4+q] = vb[q]; }
    }
    #pragma unroll
    for (int c = 0; c < NC; ++c) {
      const float* s0 = &sG[(2 + 2*c + comp)*256 + fm*16 + base];
      f32x4 va = *(const f32x4*)s0, vb = *(const f32x4*)(s0 + 4);
      #pragma unroll
      for (int q = 0; q < 4; ++q) { Gcv[c][q] = va[q]; Gcv[c][4+q] = vb[q]; }
    }
  }
  // L-const fragments: LF = straight (T's TiB == J-re's A, identical data);
  // TrB = LF negated for fq>=2; LS = swapped+neg(fq<2) (J-im's A).
  short8 LFh[KL], LFl[KL], TrBh[KL], TrBl[KL], LSh[KL], LSl[KL];
  #pragma unroll
  for (int k = 0; k < KL; ++k) {
    LFh[k] = ldfrag(&sLh[k][fOff]);
    LFl[k] = ldfrag(&sLl[k][fOff]);
    TrBh[k] = (fq >= 2) ? negbf8(LFh[k]) : LFh[k];
    TrBl[k] = (fq >= 2) ? negbf8(LFl[k]) : LFl[k];
    short8 h = ldfrag(&sLh[k][fOffS]);
    short8 l = ldfrag(&sLl[k][fOffS]);
    if (fq < 2) { h = negbf8(h); l = negbf8(l); }
    LSh[k] = h; LSl[k] = l;
  }
  // rho C-layout state (lane owns rho[4fq+q][fm], re and im)
  f32x4 rmr, rmi;
  #pragma unroll
  for (int q = 0; q < 4; ++q) {
    rmr[q] = ldval(g_r0re, b*256 + (4*fq + q)*16 + fm, isf32);
    rmi[q] = ldval(g_r0im, b*256 + (4*fq + q)*16 + fm, isf32);
  }

  const f32x4 zero = {0.f, 0.f, 0.f, 0.f};

  // ---- main Euler loop: single wave, zero barriers ----
  #pragma unroll 1
  for (int t = 0; t < NTS; ++t) {
    // G(t) fragment (registers only; overlaps the rho reads below)
    f32x4 uv = *(const f32x4*)&sU[t][0];
    float gv[8];
    #pragma unroll
    for (int q = 0; q < 8; ++q)
      gv[q] = G0v[q] + uv[0]*Gcv[0][q] + uv[1]*Gcv[1][q] + uv[2]*Gcv[2][q] + uv[3]*Gcv[3][q];
    short8 Ah, Al;
    pack8a(gv, Ah, Al);

    // rho fragments from f32 scratch (straight + swapped windows), pack = split2 bits
    f32x4 pa = *(const f32x4*)&sPf[fm*FS + fq*8];
    f32x4 pb = *(const f32x4*)&sPf[fm*FS + fq*8 + 4];
    f32x4 qa = *(const f32x4*)&sPf[fm*FS + swp];
    f32x4 qb = *(const f32x4*)&sPf[fm*FS + swp + 4];
    short8 Pfh, Pfl, Psh, Psl;
    pack8v(pa, pb, Pfh, Pfl);
    pack8v(qa, qb, Psh, Psl);
    short8 Mrh = (fq >= 2) ? negbf8(Pfh) : Pfh;
    short8 Mrl = (fq >= 2) ? negbf8(Pfl) : Pfl;

    // M components (lane owns M[4fq+q][fm] — this IS d1)
    f32x4 mR = mm3(Ah, Al, Mrh, Mrl, zero);
    f32x4 mI = mm3(Ah, Al, Psh, Psl, zero);

    // T_k tiles, C-layout accs
    f32x4 tr0 = mm3(Pfh, Pfl, TrBh[0], TrBl[0], zero);
    f32x4 ti0 = mm3(Psh, Psl, LFh[0],  LFl[0],  zero);
    f32x4 tr1 = mm3(Pfh, Pfl, TrBh[1], TrBl[1], zero);
    f32x4 ti1 = mm3(Psh, Psl, LFh[1],  LFl[1],  zero);
    f32x4 tr2 = mm3(Pfh, Pfl, TrBh[2], TrBl[2], zero);
    f32x4 ti2 = mm3(Psh, Psl, LFh[2],  LFl[2],  zero);
    f32x4 tr3 = mm3(Pfh, Pfl, TrBh[3], TrBl[3], zero);
    f32x4 ti3 = mm3(Psh, Psl, LFh[3],  LFl[3],  zero);

    // same-wave scratch writes (C-layout -> row-major f32): sTf[k][fm][4fq+q]=tr[q]
    *(f32x4*)&sTf[0][fm*FS + 4*fq]      = tr0;
    *(f32x4*)&sTf[0][fm*FS + 16 + 4*fq] = ti0;
    *(f32x4*)&sTf[1][fm*FS + 4*fq]      = tr1;
    *(f32x4*)&sTf[1][fm*FS + 16 + 4*fq] = ti1;
    *(f32x4*)&sTf[2][fm*FS + 4*fq]      = tr2;
    *(f32x4*)&sTf[2][fm*FS + 16 + 4*fq] = ti2;
    *(f32x4*)&sTf[3][fm*FS + 4*fq]      = tr3;
    *(f32x4*)&sTf[3][fm*FS + 16 + 4*fq] = ti3;
    *(f32x4*)&sMr[fm*FS + 4*fq] = mR;
    *(f32x4*)&sMi[fm*FS + 4*fq] = mI;

    // same-wave read-back: T B-fragments (window fq*8 of the 32-wide row) + pack
    short8 Th[KL], Tl[KL];
    #pragma unroll
    for (int k = 0; k < KL; ++k) {
      f32x4 ta = *(const f32x4*)&sTf[k][fm*FS + fq*8];
      f32x4 tb = *(const f32x4*)&sTf[k][fm*FS + fq*8 + 4];
      pack8v(ta, tb, Th[k], Tl[k]);
    }
    // M-transpose elements: d2r[q] = Mr[fm][4fq+q] = sMr[(4fq+q)*FS + fm]
    f32x4 d2r, d2i;
    #pragma unroll
    for (int q = 0; q < 4; ++q) {
      d2r[q] = sMr[(4*fq + q)*FS + fm];
      d2i[q] = sMi[(4*fq + q)*FS + fm];
    }

    // J components (A = L-const frags, B = T frags), 4 independent chains + tree sum
    f32x4 r0 = mm3(LFh[0], LFl[0], Th[0], Tl[0], zero);
    f32x4 r1 = mm3(LFh[1], LFl[1], Th[1], Tl[1], zero);
    f32x4 r2 = mm3(LFh[2], LFl[2], Th[2], Tl[2], zero);
    f32x4 r3 = mm3(LFh[3], LFl[3], Th[3], Tl[3], zero);
    f32x4 i0 = mm3(LSh[0], LSl[0], Th[0], Tl[0], zero);
    f32x4 i1 = mm3(LSh[1], LSl[1], Th[1], Tl[1], zero);
    f32x4 i2 = mm3(LSh[2], LSl[2], Th[2], Tl[2], zero);
    f32x4 i3 = mm3(LSh[3], LSl[3], Th[3], Tl[3], zero);

    // Euler update (signs verbatim from R0-verified wv6/wv7 paths)
    #pragma unroll
    for (int q = 0; q < 4; ++q) {
      rmr[q] += DTF * (mR[q] + d2r[q] + ((r0[q] + r1[q]) + (r2[q] + r3[q])));
      rmi[q] += DTF * (mI[q] - d2i[q] - ((i0[q] + i1[q]) + (i2[q] + i3[q])));
    }

    // write rho(t+1) back to f32 scratch (no packing — pack happens on read)
    *(f32x4*)&sPf[fm*FS + 4*fq]      = rmr;
    *(f32x4*)&sPf[fm*FS + 16 + 4*fq] = rmi;

    // pops: diagonal of rho_re(t+1), direct fire-and-forget global store
    const int qs = fm & 3;
    float pv = (qs == 0) ? rmr[0] : (qs == 1) ? rmr[1] : (qs == 2) ? rmr[2] : rmr[3];
    if (fq == (fm >> 2)) g_out[t*(BATCH*DIM) + b*DIM + fm] = pv;
  }
}

extern "C" void kernel_launch(void* const* d_in, const int* in_sizes, int n_in,
                              void* d_out, int out_size, void* d_ws, size_t ws_size,
                              hipStream_t stream) {
  (void)out_size; (void)d_ws; (void)ws_size;
  const void *P, *H0r, *H0i, *Hcr, *Hci, *Lr, *Li, *R0r, *R0i;
  int idx64 = -1;
  for (int q = 0; q < n_in; ++q) if (in_sizes[q] == 64) idx64 = q;
  if (idx64 == 6) {   // alphabetical fallback
    H0i = d_in[0]; H0r = d_in[1];
    Hci = d_in[2]; Hcr = d_in[3];
    Li  = d_in[4]; Lr  = d_in[5];
    P   = d_in[6];
    R0i = d_in[7]; R0r = d_in[8];
  } else {            // documented setup_inputs() dict order (R4-verified)
    P   = d_in[0];
    H0r = d_in[1]; H0i = d_in[2];
    Hcr = d_in[3]; Hci = d_in[4];
    Lr  = d_in[5]; Li  = d_in[6];
    R0r = d_in[7]; R0i = d_in[8];
  }
  lindblad_evolve<<<dim3(BATCH), dim3(128), 0, stream>>>(
      P, H0r, H0i, Hcr, Hci, Lr, Li, R0r, R0i, (float*)d_out);
}

// Round 4
// 493.611 us; speedup vs baseline: 1.4399x; 1.4399x over previous
//
#include <hip/hip_runtime.h>
#include <hip/hip_bf16.h>

#define DIM    16
#define BATCH  32
#define KL     4
#define NTS    512
#define NC     4
#define NPAR   16
#define DTF    (1.0f/512.0f)
#define BST    40     // bf16 operand row stride (ushort)

using short8  = __attribute__((ext_vector_type(8))) short;
using short4v = __attribute__((ext_vector_type(4))) short;
using f32x4   = __attribute__((ext_vector_type(4))) float;

__device__ __forceinline__ float b2f(__hip_bfloat16 x) { return __bfloat162float(x); }

__device__ __forceinline__ float ldval(const void* p, int idx, bool isf32) {
  return isf32 ? ((const float*)p)[idx]
               : __bfloat162float(((const __hip_bfloat16*)p)[idx]);
}
__device__ __forceinline__ unsigned short f2bf(float x) {   // RNE (setup/L only)
  unsigned u = __float_as_uint(x);
  unsigned r = u + 0x7FFFu + ((u >> 16) & 1u);
  return (unsigned short)(r >> 16);
}
__device__ __forceinline__ float bf2f(unsigned short h) {
  return __uint_as_float(((unsigned)h) << 16);
}
// trunc-trunc hi/lo split (R10-verified)
__device__ __forceinline__ void split2(float v, unsigned short& h, unsigned short& l) {
  unsigned u = __float_as_uint(v);
  h = (unsigned short)(u >> 16);
  float r = v - __uint_as_float(u & 0xFFFF0000u);
  l = (unsigned short)(__float_as_uint(r) >> 16);
}
__device__ __forceinline__ short8 ldfrag(const unsigned short* p) {
  return *(const short8*)p;
}
__device__ __forceinline__ short8 negbf8(short8 a) {
  union { short8 s; unsigned u[4]; } v; v.s = a;
  #pragma unroll
  for (int q = 0; q < 4; ++q) v.u[q] ^= 0x80008000u;
  return v.s;
}
// hi/lo 3-product MFMA: order hh + lh + hl (baseline mm3)
__device__ __forceinline__ f32x4 mm3(short8 Ah, short8 Al, short8 Bh, short8 Bl, f32x4 acc) {
  acc = __builtin_amdgcn_mfma_f32_16x16x32_bf16(Ah, Bh, acc, 0, 0, 0);
  acc = __builtin_amdgcn_mfma_f32_16x16x32_bf16(Al, Bh, acc, 0, 0, 0);
  acc = __builtin_amdgcn_mfma_f32_16x16x32_bf16(Ah, Bl, acc, 0, 0, 0);
  return acc;
}
// transpose-mirrored order: hh + hl + lh (so (A·B)^T via B^T·A^T sums in the SAME order)
__device__ __forceinline__ f32x4 mm3b(short8 Ah, short8 Al, short8 Bh, short8 Bl, f32x4 acc) {
  acc = __builtin_amdgcn_mfma_f32_16x16x32_bf16(Ah, Bh, acc, 0, 0, 0);
  acc = __builtin_amdgcn_mfma_f32_16x16x32_bf16(Ah, Bl, acc, 0, 0, 0);
  acc = __builtin_amdgcn_mfma_f32_16x16x32_bf16(Al, Bh, acc, 0, 0, 0);
  return acc;
}
// trunc hi/lo pack of f32x4 via v_perm_b32 — bit-identical to split2 (R0-pass-verified)
__device__ __forceinline__ void pack4(f32x4 v, short4v& hi, short4v& lo) {
  union { short4v s; unsigned d[2]; } H, L;
  unsigned u0 = __float_as_uint(v[0]), u1 = __float_as_uint(v[1]);
  unsigned u2 = __float_as_uint(v[2]), u3 = __float_as_uint(v[3]);
  H.d[0] = __builtin_amdgcn_perm(u1, u0, 0x07060302u);
  H.d[1] = __builtin_amdgcn_perm(u3, u2, 0x07060302u);
  float r0 = v[0] - __uint_as_float(u0 & 0xFFFF0000u);
  float r1 = v[1] - __uint_as_float(u1 & 0xFFFF0000u);
  float r2 = v[2] - __uint_as_float(u2 & 0xFFFF0000u);
  float r3 = v[3] - __uint_as_float(u3 & 0xFFFF0000u);
  L.d[0] = __builtin_amdgcn_perm(__float_as_uint(r1), __float_as_uint(r0), 0x07060302u);
  L.d[1] = __builtin_amdgcn_perm(__float_as_uint(r3), __float_as_uint(r2), 0x07060302u);
  hi = H.s; lo = L.s;
}
__device__ __forceinline__ void pack8(const float* v, short8& hi, short8& lo) {
  union { short8 s; unsigned d[4]; } H, L;
  #pragma unroll
  for (int j = 0; j < 4; ++j) {
    unsigned ua = __float_as_uint(v[2*j]), ub = __float_as_uint(v[2*j+1]);
    H.d[j] = __builtin_amdgcn_perm(ub, ua, 0x07060302u);
    float ra = v[2*j]   - __uint_as_float(ua & 0xFFFF0000u);
    float rb = v[2*j+1] - __uint_as_float(ub & 0xFFFF0000u);
    L.d[j] = __builtin_amdgcn_perm(__float_as_uint(rb), __float_as_uint(ra), 0x07060302u);
  }
  hi = H.s; lo = L.s;
}

// R3: 6-wave structure = baseline 8-wave minus the M-waves. The update waves (wv4=re,
// wv5=im) compute Mr/Mr^T resp. Mi/Mi^T THEMSELVES in phase 1 via the G^T-fragment
// identity (B-frag of G^T == A-frag gv, sign-flipped on fq>=2 for the re-part), so the
// entire M LDS round-trip (sMr/sMi/sMrT/sMiT, 2 producer waves, phase-2 M reads) is
// deleted. T-producer waves (wv0-3) and all fragment layouts/signs are verbatim from
// the verified baseline. 2 barriers/step.
__global__ __launch_bounds__(384, 1)
void lindblad_evolve(const void* __restrict__ g_params,
                     const void* __restrict__ g_H0re, const void* __restrict__ g_H0im,
                     const void* __restrict__ g_Hcre, const void* __restrict__ g_Hcim,
                     const void* __restrict__ g_Lre,  const void* __restrict__ g_Lim,
                     const void* __restrict__ g_r0re, const void* __restrict__ g_r0im,
                     float* __restrict__ g_out)
{
  __shared__ __align__(16) unsigned short sPh[16*BST], sPl[16*BST];         // rho^T' hi/lo
  __shared__ __align__(16) unsigned short sTh[KL][16*BST], sTl[KL][16*BST]; // T_k row-major [Tr|Ti]
  __shared__ __align__(16) unsigned short sLh[KL][16*BST], sLl[KL][16*BST]; // L'_k
  __shared__ __align__(16) float sU[NTS][NC];
  __shared__ __align__(16) float sPops[NTS*DIM];  // pops; first 2560 f32 = setup G-scratch
  __shared__ int sFlag;

  const int tid = threadIdx.x;       // 0..383 (6 waves)
  const int b   = blockIdx.x;
  const int wv  = tid >> 6;          // 0-3: T_k | 4: re-update | 5: im-update
  const int ln  = tid & 63;
  const int fm  = ln & 15;
  const int fq  = ln >> 4;
  const int row0 = fq * 4;
  const int fOff  = fm*BST + fq*8;
  const int fOffS = fm*BST + ((fq*8 + 16) & 31);

  // ---- input storage-dtype detection (R1/R2-verified) ----
  if (tid == 0) sFlag = 0;
  __syncthreads();
  if (tid < 256) {
    float v = b2f(((const __hip_bfloat16*)g_H0re)[tid]);
    if (!(fabsf(v) <= 1e10f)) atomicOr(&sFlag, 1);
  }
  __syncthreads();
  const bool isf32 = (sFlag != 0);

  // ---- B-spline control pulses (384 threads, strided) ----
  for (int t0 = tid; t0 < NTS; t0 += 384) {
    float kn[20];
    kn[0] = 0.f; kn[1] = 0.f; kn[2] = 0.f;
    #pragma unroll
    for (int q = 0; q < 14; ++q) kn[3 + q] = (float)q / 13.0f;
    kn[17] = 1.f; kn[18] = 1.f; kn[19] = 1.f;
    const float t = (float)t0 * DTF;
    float B[19];
    #pragma unroll
    for (int q = 0; q < 19; ++q) B[q] = (kn[q] <= t && t < kn[q+1]) ? 1.f : 0.f;
    #pragma unroll
    for (int d = 1; d <= 3; ++d) {
      #pragma unroll
      for (int q = 0; q + d < 19; ++q) {
        float ld = kn[q+d]   - kn[q];
        float rd = kn[q+d+1] - kn[q+1];
        float lv = (ld > 0.f) ? (t - kn[q])     / ld * B[q]   : 0.f;
        float rv = (rd > 0.f) ? (kn[q+d+1] - t) / rd * B[q+1] : 0.f;
        B[q] = lv + rv;
      }
    }
    #pragma unroll
    for (int c = 0; c < NC; ++c) {
      float s = 0.f;
      #pragma unroll
      for (int q = 0; q < NPAR; ++q) s += B[q] * ldval(g_params, q*NC + c, isf32);
      sU[t0][c] = s;
    }
  }

  // ---- constants staging (threads 0..255, elementwise (i,j)) ----
  if (tid < 256) {
    float* scr = sPops;   // planes: 0=G0r 1=G0i 2+2c=Gc_r 3+2c=Gc_i
    const int i = tid >> 4, j = tid & 15;
    const int ij = i*16 + j, ji = j*16 + i;
    float h0r = 0.5f * (ldval(g_H0re, ij, isf32) + ldval(g_H0re, ji, isf32));
    float h0i = 0.5f * (ldval(g_H0im, ij, isf32) - ldval(g_H0im, ji, isf32));
    float ldr = 0.f, ldi = 0.f;
    for (int k = 0; k < KL; ++k) {
      #pragma unroll
      for (int m = 0; m < DIM; ++m) {
        float ar = ldval(g_Lre, k*256 + m*16 + i, isf32), ai = ldval(g_Lim, k*256 + m*16 + i, isf32);
        float br = ldval(g_Lre, k*256 + m*16 + j, isf32), bi = ldval(g_Lim, k*256 + m*16 + j, isf32);
        ldr += ar*br + ai*bi;
        ldi += ar*bi - ai*br;
      }
    }
    scr[0*256 + ij] =  h0i - 0.5f*ldr;   // G0r
    scr[1*256 + ij] = -h0r - 0.5f*ldi;   // G0i
    #pragma unroll
    for (int c = 0; c < NC; ++c) {
      float hr = 0.5f * (ldval(g_Hcre, c*256 + ij, isf32) + ldval(g_Hcre, c*256 + ji, isf32));
      float hi = 0.5f * (ldval(g_Hcim, c*256 + ij, isf32) - ldval(g_Hcim, c*256 + ji, isf32));
      scr[(2 + 2*c)*256 + ij] =  hi;
      scr[(3 + 2*c)*256 + ij] = -hr;
    }
    // L': RNE hi/lo split
    #pragma unroll
    for (int k = 0; k < KL; ++k) {
      float lr = ldval(g_Lre, k*256 + ij, isf32);
      float li = ldval(g_Lim, k*256 + ij, isf32);
      unsigned short h;
      h = f2bf(lr); sLh[k][i*BST + j]      = h; sLl[k][i*BST + j]      = f2bf(lr - bf2f(h));
      h = f2bf(li); sLh[k][i*BST + 16 + j] = h; sLl[k][i*BST + 16 + j] = f2bf(li - bf2f(h));
    }
    // rho^T'(0)
    float r0 = ldval(g_r0re, b*256 + ij, isf32);
    float m0 = ldval(g_r0im, b*256 + ij, isf32);
    unsigned short h, l;
    split2(r0, h, l); sPh[j*BST + i]      = h; sPl[j*BST + i]      = l;
    split2(m0, h, l); sPh[j*BST + 16 + i] = h; sPl[j*BST + 16 + i] = l;
  }

  __syncthreads();   // scratch, sL, sP, sU visible

  // ---- per-wave preloads ----
  short8 Ah, Al;                    // wv4/5: G A-frag (rebuilt per step)
  short8 TrBh, TrBl, TiBh, TiBl;    // wv0-3: T^T B-operands (L-derived constants)
  short8 JBh[KL], JBl[KL];          // wv4: straight Lf; wv5: swap+neg
  float  G0v[8], Gcv[NC][8];        // wv4/5
  float  rm[4] = {0.f,0.f,0.f,0.f}; // wv4: rho_re; wv5: rho_im (C-layout)

  if (wv >= 4) {
    // G plane windows for the A-fragment (baseline wv0/1 preload, verbatim)
    const int comp = (fq < 2) ? 0 : 1;
    const int base = (fq & 1) * 8;
    const float* scr = sPops;
    {
      const float* s0 = &scr[comp*256 + fm*16 + base];
      f32x4 va = *(const f32x4*)s0, vb = *(const f32x4*)(s0 + 4);
      #pragma unroll
      for (int q = 0; q < 4; ++q) { G0v[q] = va[q]; G0v[4+q] = vb[q]; }
    }
    #pragma unroll
    for (int c = 0; c < NC; ++c) {
      const float* s0 = &scr[(2 + 2*c + comp)*256 + fm*16 + base];
      f32x4 va = *(const f32x4*)s0, vb = *(const f32x4*)(s0 + 4);
      #pragma unroll
      for (int q = 0; q < 4; ++q) { Gcv[c][q] = va[q]; Gcv[c][4+q] = vb[q]; }
    }
    f32x4 uv = *(const f32x4*)&sU[0][0];
    float gv[8];
    #pragma unroll
    for (int q = 0; q < 8; ++q)
      gv[q] = G0v[q] + uv[0]*Gcv[0][q] + uv[1]*Gcv[1][q] + uv[2]*Gcv[2][q] + uv[3]*Gcv[3][q];
    pack8(gv, Ah, Al);
    if (wv == 4) {
      // Jr^T A-operands = straight L-frags (baseline wv6)
      #pragma unroll
      for (int k = 0; k < KL; ++k) { JBh[k] = ldfrag(&sLh[k][fOff]); JBl[k] = ldfrag(&sLl[k][fOff]); }
      #pragma unroll
      for (int q = 0; q < 4; ++q) rm[q] = ldval(g_r0re, b*256 + (row0+q)*16 + fm, isf32);
    } else {
      // Ji^T A-operands = swap+neg L-frags (baseline wv7)
      #pragma unroll
      for (int k = 0; k < KL; ++k) {
        short8 h = ldfrag(&sLh[k][fOffS]);
        short8 l = ldfrag(&sLl[k][fOffS]);
        if (fq < 2) { h = negbf8(h); l = negbf8(l); }
        JBh[k] = h; JBl[k] = l;
      }
      #pragma unroll
      for (int q = 0; q < 4; ++q) rm[q] = ldval(g_r0im, b*256 + (row0+q)*16 + fm, isf32);
    }
  } else {
    // T^T path constants for k = wv (baseline wv2-5, verbatim)
    const int k = wv;
    TiBh = ldfrag(&sLh[k][fOff]);
    TiBl = ldfrag(&sLl[k][fOff]);
    TrBh = (fq >= 2) ? negbf8(TiBh) : TiBh;
    TrBl = (fq >= 2) ? negbf8(TiBl) : TiBl;
  }

  const f32x4 zero = {0.f, 0.f, 0.f, 0.f};

  // ---- main Euler loop: 2 barriers/step, 6 waves ----
  #pragma unroll 1
  for (int t = 0; t < NTS; ++t) {
    f32x4 mAcc, mtAcc;   // wv4: Mr, Mr^T; wv5: Mi, Mi^T (own C-layout elements)

    __syncthreads();   // B1: sP(t) visible

    if (wv < 4) {
      // ---- T^T producer (baseline wv2-5, verbatim): A = rho-frags, B = L-consts ----
      const int k = wv;
      short8 Arh = ldfrag(&sPh[fOff]),  Arl = ldfrag(&sPl[fOff]);    // [rho_r^T|rho_i^T]
      short8 Aih = ldfrag(&sPh[fOffS]), Ail = ldfrag(&sPl[fOffS]);   // [rho_i^T|rho_r^T]
      f32x4 tr = zero, ti = zero;
      tr = mm3(Arh, Arl, TrBh, TrBl, tr);    // Tr^T tile
      ti = mm3(Aih, Ail, TiBh, TiBl, ti);    // Ti^T tile
      short4v HR, LR, HI2, LI2;
      pack4(tr, HR, LR);
      pack4(ti, HI2, LI2);
      *(short4v*)&sTh[k][fm*BST + row0]      = HR;
      *(short4v*)&sTl[k][fm*BST + row0]      = LR;
      *(short4v*)&sTh[k][fm*BST + 16 + row0] = HI2;
      *(short4v*)&sTl[k][fm*BST + 16 + row0] = LI2;
    } else if (wv == 4) {
      // ---- Mr and Mr^T in registers ----
      short8 Ph = ldfrag(&sPh[fOff]), Pl = ldfrag(&sPl[fOff]);       // [rho_r^T|rho_i^T]
      short8 Bh = (fq >= 2) ? negbf8(Ph) : Ph;                       // B = [rho_r; -rho_i]
      short8 Bl = (fq >= 2) ? negbf8(Pl) : Pl;
      mAcc = mm3(Ah, Al, Bh, Bl, zero);                              // Mr[4fq+q][fm]
      short8 Gth = (fq >= 2) ? negbf8(Ah) : Ah;                      // B-frag of [Gr^T; -Gi^T]
      short8 Gtl = (fq >= 2) ? negbf8(Al) : Al;
      mtAcc = mm3b(Ph, Pl, Gth, Gtl, zero);                          // Mr^T[4fq+q][fm]
    } else {
      // ---- Mi and Mi^T in registers ----
      short8 Ph = ldfrag(&sPh[fOffS]), Pl = ldfrag(&sPl[fOffS]);     // [rho_i^T|rho_r^T]
      mAcc = mm3(Ah, Al, Ph, Pl, zero);                              // Mi[4fq+q][fm]
      mtAcc = mm3b(Ph, Pl, Ah, Al, zero);                            // Mi^T[4fq+q][fm]
    }

    __syncthreads();   // B2: sT visible

    if (wv >= 4) {
      // ---- J^T + update (baseline wv6/7 with d1,d2 from own accs) ----
      short8 T0h = ldfrag(&sTh[0][fOff]), T0l = ldfrag(&sTl[0][fOff]);
      short8 T1h = ldfrag(&sTh[1][fOff]), T1l = ldfrag(&sTl[1][fOff]);
      short8 T2h = ldfrag(&sTh[2][fOff]), T2l = ldfrag(&sTl[2][fOff]);
      short8 T3h = ldfrag(&sTh[3][fOff]), T3l = ldfrag(&sTl[3][fOff]);
      f32x4 a0 = zero, a1 = zero, a2 = zero, a3 = zero;
      a0 = mm3(JBh[0], JBl[0], T0h, T0l, a0);
      a1 = mm3(JBh[1], JBl[1], T1h, T1l, a1);
      a2 = mm3(JBh[2], JBl[2], T2h, T2l, a2);
      a3 = mm3(JBh[3], JBl[3], T3h, T3l, a3);

      short4v HH, LL;
      f32x4 rv;
      if (wv == 4) {
        #pragma unroll
        for (int q = 0; q < 4; ++q) {
          rm[q] += DTF * (mAcc[q] + mtAcc[q] + ((a0[q] + a1[q]) + (a2[q] + a3[q])));
          rv[q] = rm[q];
        }
        pack4(rv, HH, LL);
        *(short4v*)&sPh[fm*BST + row0] = HH;
        *(short4v*)&sPl[fm*BST + row0] = LL;
        if ((unsigned)(fm - row0) < 4u) sPops[t*DIM + fm] = rm[fm - row0];
      } else {
        #pragma unroll
        for (int q = 0; q < 4; ++q) {
          // Ji^T = -Ji at own element -> subtract; -Mi^T from mtAcc
          rm[q] += DTF * (mAcc[q] - mtAcc[q] - ((a0[q] + a1[q]) + (a2[q] + a3[q])));
          rv[q] = rm[q];
        }
        pack4(rv, HH, LL);
        *(short4v*)&sPh[fm*BST + 16 + row0] = HH;
        *(short4v*)&sPl[fm*BST + 16 + row0] = LL;
      }

      // ---- G-rebuild for step t+1 (registers only, after the stores) ----
      const int tn = (t + 1 < NTS) ? (t + 1) : t;
      f32x4 uv = *(const f32x4*)&sU[tn][0];
      float gv[8];
      #pragma unroll
      for (int q = 0; q < 8; ++q)
        gv[q] = G0v[q] + uv[0]*Gcv[0][q] + uv[1]*Gcv[1][q] + uv[2]*Gcv[2][q] + uv[3]*Gcv[3][q];
      pack8(gv, Ah, Al);
    }
    // wv0-3: idle in phase 2
  }

  // ---- final coalesced pops flush (float4), 384-thread strided ----
  __syncthreads();
  for (int i4 = tid; i4 < NTS*DIM/4; i4 += 384) {
    int idx = i4 * 4;                            // idx = t*16 + d, d 4-aligned
    int tt = idx >> 4, dd = idx & 15;
    *(float4*)&g_out[tt*(BATCH*DIM) + b*DIM + dd] = *(const float4*)&sPops[idx];
  }
}

extern "C" void kernel_launch(void* const* d_in, const int* in_sizes, int n_in,
                              void* d_out, int out_size, void* d_ws, size_t ws_size,
                              hipStream_t stream) {
  (void)out_size; (void)d_ws; (void)ws_size;
  const void *P, *H0r, *H0i, *Hcr, *Hci, *Lr, *Li, *R0r, *R0i;
  int idx64 = -1;
  for (int q = 0; q < n_in; ++q) if (in_sizes[q] == 64) idx64 = q;
  if (idx64 == 6) {   // alphabetical fallback
    H0i = d_in[0]; H0r = d_in[1];
    Hci = d_in[2]; Hcr = d_in[3];
    Li  = d_in[4]; Lr  = d_in[5];
    P   = d_in[6];
    R0i = d_in[7]; R0r = d_in[8];
  } else {            // documented setup_inputs() dict order (R4-verified)
    P   = d_in[0];
    H0r = d_in[1]; H0i = d_in[2];
    Hcr = d_in[3]; Hci = d_in[4];
    Lr  = d_in[5]; Li  = d_in[6];
    R0r = d_in[7]; R0i = d_in[8];
  }
  lindblad_evolve<<<dim3(BATCH), dim3(384), 0, stream>>>(
      P, H0r, H0i, Hcr, Hci, Lr, Li, R0r, R0i, (float*)d_out);
}

// Round 5
// 417.768 us; speedup vs baseline: 1.7013x; 1.1815x over previous
//
#include <hip/hip_runtime.h>
#include <hip/hip_bf16.h>

#define DIM    16
#define BATCH  32
#define KL     4
#define NTS    512
#define NC     4
#define NPAR   16
#define DTF    (1.0f/512.0f)
#define BST    40     // bf16 operand row stride (ushort)

using short8  = __attribute__((ext_vector_type(8))) short;
using short4v = __attribute__((ext_vector_type(4))) short;
using f32x4   = __attribute__((ext_vector_type(4))) float;

__device__ __forceinline__ float b2f(__hip_bfloat16 x) { return __bfloat162float(x); }

__device__ __forceinline__ float ldval(const void* p, int idx, bool isf32) {
  return isf32 ? ((const float*)p)[idx]
               : __bfloat162float(((const __hip_bfloat16*)p)[idx]);
}
__device__ __forceinline__ unsigned short f2bf(float x) {   // RNE (setup/L only)
  unsigned u = __float_as_uint(x);
  unsigned r = u + 0x7FFFu + ((u >> 16) & 1u);
  return (unsigned short)(r >> 16);
}
__device__ __forceinline__ float bf2f(unsigned short h) {
  return __uint_as_float(((unsigned)h) << 16);
}
// trunc-trunc hi/lo split (verified)
__device__ __forceinline__ void split2(float v, unsigned short& h, unsigned short& l) {
  unsigned u = __float_as_uint(v);
  h = (unsigned short)(u >> 16);
  float r = v - __uint_as_float(u & 0xFFFF0000u);
  l = (unsigned short)(__float_as_uint(r) >> 16);
}
__device__ __forceinline__ short8 ldfrag(const unsigned short* p) {
  return *(const short8*)p;
}
__device__ __forceinline__ short8 negbf8(short8 a) {
  union { short8 s; unsigned u[4]; } v; v.s = a;
  #pragma unroll
  for (int q = 0; q < 4; ++q) v.u[q] ^= 0x80008000u;
  return v.s;
}
// hi/lo 3-product MFMA: order hh + lh + hl (baseline mm3)
__device__ __forceinline__ f32x4 mm3(short8 Ah, short8 Al, short8 Bh, short8 Bl, f32x4 acc) {
  acc = __builtin_amdgcn_mfma_f32_16x16x32_bf16(Ah, Bh, acc, 0, 0, 0);
  acc = __builtin_amdgcn_mfma_f32_16x16x32_bf16(Al, Bh, acc, 0, 0, 0);
  acc = __builtin_amdgcn_mfma_f32_16x16x32_bf16(Ah, Bl, acc, 0, 0, 0);
  return acc;
}
// transpose-mirrored order: hh + hl + lh (R3-verified for M^T)
__device__ __forceinline__ f32x4 mm3b(short8 Ah, short8 Al, short8 Bh, short8 Bl, f32x4 acc) {
  acc = __builtin_amdgcn_mfma_f32_16x16x32_bf16(Ah, Bh, acc, 0, 0, 0);
  acc = __builtin_amdgcn_mfma_f32_16x16x32_bf16(Ah, Bl, acc, 0, 0, 0);
  acc = __builtin_amdgcn_mfma_f32_16x16x32_bf16(Al, Bh, acc, 0, 0, 0);
  return acc;
}
// trunc hi/lo pack of f32x4 via v_perm_b32 — bit-identical to split2 (verified)
__device__ __forceinline__ void pack4(f32x4 v, short4v& hi, short4v& lo) {
  union { short4v s; unsigned d[2]; } H, L;
  unsigned u0 = __float_as_uint(v[0]), u1 = __float_as_uint(v[1]);
  unsigned u2 = __float_as_uint(v[2]), u3 = __float_as_uint(v[3]);
  H.d[0] = __builtin_amdgcn_perm(u1, u0, 0x07060302u);
  H.d[1] = __builtin_amdgcn_perm(u3, u2, 0x07060302u);
  float r0 = v[0] - __uint_as_float(u0 & 0xFFFF0000u);
  float r1 = v[1] - __uint_as_float(u1 & 0xFFFF0000u);
  float r2 = v[2] - __uint_as_float(u2 & 0xFFFF0000u);
  float r3 = v[3] - __uint_as_float(u3 & 0xFFFF0000u);
  L.d[0] = __builtin_amdgcn_perm(__float_as_uint(r1), __float_as_uint(r0), 0x07060302u);
  L.d[1] = __builtin_amdgcn_perm(__float_as_uint(r3), __float_as_uint(r2), 0x07060302u);
  hi = H.s; lo = L.s;
}
__device__ __forceinline__ void pack8(const float* v, short8& hi, short8& lo) {
  union { short8 s; unsigned d[4]; } H, L;
  #pragma unroll
  for (int j = 0; j < 4; ++j) {
    unsigned ua = __float_as_uint(v[2*j]), ub = __float_as_uint(v[2*j+1]);
    H.d[j] = __builtin_amdgcn_perm(ub, ua, 0x07060302u);
    float ra = v[2*j]   - __uint_as_float(ua & 0xFFFF0000u);
    float rb = v[2*j+1] - __uint_as_float(ub & 0xFFFF0000u);
    L.d[j] = __builtin_amdgcn_perm(__float_as_uint(rb), __float_as_uint(ra), 0x07060302u);
  }
  hi = H.s; lo = L.s;
}

// R4: k-parallel 6-wave structure.
//   wv0-3 (k-waves): phase 1 = T_k (rho -> C-layout acc -> same-wave LDS roundtrip ->
//     B-frag) THEN Jr_k, Ji_k = mm3(L-frag, T-frag); partial J's written as C-layout
//     f32x4 to lane-aligned slots (transpose-free handoff). Phase 2 (wv0 only):
//     G(t+1)-fragment rebuild, passed via a 16x32 hi/lo LDS tile.
//   wv4/5 (update waves): phase 1 = Mr/Mr^T resp. Mi/Mi^T in registers (R3-verified,
//     G-frag now ldfrag'd from the LDS tile — identical bytes). Phase 2 = read 4 J
//     slots + tree-sum + Euler update + pack + write rho (baseline-verified formulas).
// All cross-wave RAW deps cross exactly one barrier; the T->J transpose is the
// R2-verified same-wave LDS roundtrip (in-order DS pipe). 2 barriers/step.
__global__ __launch_bounds__(384, 1)
void lindblad_evolve(const void* __restrict__ g_params,
                     const void* __restrict__ g_H0re, const void* __restrict__ g_H0im,
                     const void* __restrict__ g_Hcre, const void* __restrict__ g_Hcim,
                     const void* __restrict__ g_Lre,  const void* __restrict__ g_Lim,
                     const void* __restrict__ g_r0re, const void* __restrict__ g_r0im,
                     float* __restrict__ g_out)
{
  __shared__ __align__(16) unsigned short sPh[16*BST], sPl[16*BST];         // rho^T' hi/lo
  __shared__ __align__(16) unsigned short sTh[KL][16*BST], sTl[KL][16*BST]; // T_k roundtrip (per-wave private)
  __shared__ __align__(16) unsigned short sLh[KL][16*BST], sLl[KL][16*BST]; // L'_k
  __shared__ __align__(16) unsigned short sGh[16*BST], sGl[16*BST];         // G(t) frag tile hi/lo
  __shared__ __align__(16) float sJr[KL][256], sJi[KL][256];                // J_k partials, lane slots
  __shared__ __align__(16) float sU[NTS][NC];
  __shared__ __align__(16) float sPops[NTS*DIM];  // pops; first 2560 f32 = setup G-scratch
  __shared__ int sFlag;

  const int tid = threadIdx.x;       // 0..383 (6 waves)
  const int b   = blockIdx.x;
  const int wv  = tid >> 6;          // 0-3: k-waves | 4: re-update | 5: im-update
  const int ln  = tid & 63;
  const int fm  = ln & 15;
  const int fq  = ln >> 4;
  const int row0 = fq * 4;
  const int fOff  = fm*BST + fq*8;
  const int fOffS = fm*BST + ((fq*8 + 16) & 31);

  // ---- input storage-dtype detection (verified) ----
  if (tid == 0) sFlag = 0;
  __syncthreads();
  if (tid < 256) {
    float v = b2f(((const __hip_bfloat16*)g_H0re)[tid]);
    if (!(fabsf(v) <= 1e10f)) atomicOr(&sFlag, 1);
  }
  __syncthreads();
  const bool isf32 = (sFlag != 0);

  // ---- B-spline control pulses (384 threads, strided) ----
  for (int t0 = tid; t0 < NTS; t0 += 384) {
    float kn[20];
    kn[0] = 0.f; kn[1] = 0.f; kn[2] = 0.f;
    #pragma unroll
    for (int q = 0; q < 14; ++q) kn[3 + q] = (float)q / 13.0f;
    kn[17] = 1.f; kn[18] = 1.f; kn[19] = 1.f;
    const float t = (float)t0 * DTF;
    float B[19];
    #pragma unroll
    for (int q = 0; q < 19; ++q) B[q] = (kn[q] <= t && t < kn[q+1]) ? 1.f : 0.f;
    #pragma unroll
    for (int d = 1; d <= 3; ++d) {
      #pragma unroll
      for (int q = 0; q + d < 19; ++q) {
        float ld = kn[q+d]   - kn[q];
        float rd = kn[q+d+1] - kn[q+1];
        float lv = (ld > 0.f) ? (t - kn[q])     / ld * B[q]   : 0.f;
        float rv = (rd > 0.f) ? (kn[q+d+1] - t) / rd * B[q+1] : 0.f;
        B[q] = lv + rv;
      }
    }
    #pragma unroll
    for (int c = 0; c < NC; ++c) {
      float s = 0.f;
      #pragma unroll
      for (int q = 0; q < NPAR; ++q) s += B[q] * ldval(g_params, q*NC + c, isf32);
      sU[t0][c] = s;
    }
  }

  // ---- constants staging (threads 0..255, elementwise (i,j)) ----
  if (tid < 256) {
    float* scr = sPops;   // planes: 0=G0r 1=G0i 2+2c=Gc_r 3+2c=Gc_i
    const int i = tid >> 4, j = tid & 15;
    const int ij = i*16 + j, ji = j*16 + i;
    float h0r = 0.5f * (ldval(g_H0re, ij, isf32) + ldval(g_H0re, ji, isf32));
    float h0i = 0.5f * (ldval(g_H0im, ij, isf32) - ldval(g_H0im, ji, isf32));
    float ldr = 0.f, ldi = 0.f;
    for (int k = 0; k < KL; ++k) {
      #pragma unroll
      for (int m = 0; m < DIM; ++m) {
        float ar = ldval(g_Lre, k*256 + m*16 + i, isf32), ai = ldval(g_Lim, k*256 + m*16 + i, isf32);
        float br = ldval(g_Lre, k*256 + m*16 + j, isf32), bi = ldval(g_Lim, k*256 + m*16 + j, isf32);
        ldr += ar*br + ai*bi;
        ldi += ar*bi - ai*br;
      }
    }
    scr[0*256 + ij] =  h0i - 0.5f*ldr;   // G0r
    scr[1*256 + ij] = -h0r - 0.5f*ldi;   // G0i
    #pragma unroll
    for (int c = 0; c < NC; ++c) {
      float hr = 0.5f * (ldval(g_Hcre, c*256 + ij, isf32) + ldval(g_Hcre, c*256 + ji, isf32));
      float hi = 0.5f * (ldval(g_Hcim, c*256 + ij, isf32) - ldval(g_Hcim, c*256 + ji, isf32));
      scr[(2 + 2*c)*256 + ij] =  hi;
      scr[(3 + 2*c)*256 + ij] = -hr;
    }
    // L': RNE hi/lo split
    #pragma unroll
    for (int k = 0; k < KL; ++k) {
      float lr = ldval(g_Lre, k*256 + ij, isf32);
      float li = ldval(g_Lim, k*256 + ij, isf32);
      unsigned short h;
      h = f2bf(lr); sLh[k][i*BST + j]      = h; sLl[k][i*BST + j]      = f2bf(lr - bf2f(h));
      h = f2bf(li); sLh[k][i*BST + 16 + j] = h; sLl[k][i*BST + 16 + j] = f2bf(li - bf2f(h));
    }
    // rho^T'(0)
    float r0 = ldval(g_r0re, b*256 + ij, isf32);
    float m0 = ldval(g_r0im, b*256 + ij, isf32);
    unsigned short h, l;
    split2(r0, h, l); sPh[j*BST + i]      = h; sPl[j*BST + i]      = l;
    split2(m0, h, l); sPh[j*BST + 16 + i] = h; sPl[j*BST + 16 + i] = l;
  }

  __syncthreads();   // scratch, sL, sP, sU visible

  // ---- per-wave preloads ----
  short8 LFh_, LFl_, TrBh_, TrBl_, LSh_, LSl_;   // k-waves: L-derived constant frags
  float  G0v[8], Gcv[NC][8];                     // wv0 only (G-rebuild owner)
  float  rm[4] = {0.f,0.f,0.f,0.f};              // wv4: rho_re; wv5: rho_im (C-layout)

  if (wv < 4) {
    const int k = wv;
    LFh_ = ldfrag(&sLh[k][fOff]);                // straight frag: Ti's B AND Jr's A
    LFl_ = ldfrag(&sLl[k][fOff]);
    TrBh_ = (fq >= 2) ? negbf8(LFh_) : LFh_;     // Tr's B
    TrBl_ = (fq >= 2) ? negbf8(LFl_) : LFl_;
    short8 h = ldfrag(&sLh[k][fOffS]);           // Ji's A: swap+neg
    short8 l = ldfrag(&sLl[k][fOffS]);
    if (fq < 2) { h = negbf8(h); l = negbf8(l); }
    LSh_ = h; LSl_ = l;
    if (wv == 0) {
      // G plane windows (baseline preload, verbatim)
      const int comp = (fq < 2) ? 0 : 1;
      const int base = (fq & 1) * 8;
      const float* scr = sPops;
      {
        const float* s0 = &scr[comp*256 + fm*16 + base];
        f32x4 va = *(const f32x4*)s0, vb = *(const f32x4*)(s0 + 4);
        #pragma unroll
        for (int q = 0; q < 4; ++q) { G0v[q] = va[q]; G0v[4+q] = vb[q]; }
      }
      #pragma unroll
      for (int c = 0; c < NC; ++c) {
        const float* s0 = &scr[(2 + 2*c + comp)*256 + fm*16 + base];
        f32x4 va = *(const f32x4*)s0, vb = *(const f32x4*)(s0 + 4);
        #pragma unroll
        for (int q = 0; q < 4; ++q) { Gcv[c][q] = va[q]; Gcv[c][4+q] = vb[q]; }
      }
      // G(0) fragment tile into LDS (same bytes as baseline's in-register pack8)
      f32x4 uv = *(const f32x4*)&sU[0][0];
      float gv[8];
      #pragma unroll
      for (int q = 0; q < 8; ++q)
        gv[q] = G0v[q] + uv[0]*Gcv[0][q] + uv[1]*Gcv[1][q] + uv[2]*Gcv[2][q] + uv[3]*Gcv[3][q];
      short8 Gh_, Gl_;
      pack8(gv, Gh_, Gl_);
      *(short8*)&sGh[fm*BST + fq*8] = Gh_;
      *(short8*)&sGl[fm*BST + fq*8] = Gl_;
    }
  } else if (wv == 4) {
    #pragma unroll
    for (int q = 0; q < 4; ++q) rm[q] = ldval(g_r0re, b*256 + (row0+q)*16 + fm, isf32);
  } else {
    #pragma unroll
    for (int q = 0; q < 4; ++q) rm[q] = ldval(g_r0im, b*256 + (row0+q)*16 + fm, isf32);
  }

  const f32x4 zero = {0.f, 0.f, 0.f, 0.f};

  // ---- main Euler loop: 2 barriers/step, 6 waves ----
  #pragma unroll 1
  for (int t = 0; t < NTS; ++t) {
    f32x4 mAcc, mtAcc;   // wv4: Mr, Mr^T; wv5: Mi, Mi^T (own C-layout elements)

    __syncthreads();   // B1: sP(t) + sG(t) visible

    if (wv < 4) {
      // ---- T_k (baseline T-wave, verbatim) ----
      const int k = wv;
      short8 Arh = ldfrag(&sPh[fOff]),  Arl = ldfrag(&sPl[fOff]);    // [rho_r^T|rho_i^T]
      short8 Aih = ldfrag(&sPh[fOffS]), Ail = ldfrag(&sPl[fOffS]);   // [rho_i^T|rho_r^T]
      f32x4 tr = mm3(Arh, Arl, TrBh_, TrBl_, zero);    // Tr^T tile
      f32x4 ti = mm3(Aih, Ail, LFh_,  LFl_,  zero);    // Ti^T tile
      short4v HR, LR, HI2, LI2;
      pack4(tr, HR, LR);
      pack4(ti, HI2, LI2);
      *(short4v*)&sTh[k][fm*BST + row0]      = HR;
      *(short4v*)&sTl[k][fm*BST + row0]      = LR;
      *(short4v*)&sTh[k][fm*BST + 16 + row0] = HI2;
      *(short4v*)&sTl[k][fm*BST + 16 + row0] = LI2;
      // ---- same-wave roundtrip read (R2-verified pattern), then J_k ----
      short8 Th = ldfrag(&sTh[k][fOff]), Tl = ldfrag(&sTl[k][fOff]);
      f32x4 jr = mm3(LFh_, LFl_, Th, Tl, zero);   // Jr_k contribution (C-layout)
      f32x4 ji = mm3(LSh_, LSl_, Th, Tl, zero);   // Ji_k contribution (C-layout)
      *(f32x4*)&sJr[k][ln*4] = jr;                // lane-aligned slot, no transpose
      *(f32x4*)&sJi[k][ln*4] = ji;
    } else if (wv == 4) {
      // ---- Mr and Mr^T in registers (R3-verified; G-frag from LDS tile) ----
      short8 Ah = ldfrag(&sGh[fOff]), Al = ldfrag(&sGl[fOff]);
      short8 Ph = ldfrag(&sPh[fOff]), Pl = ldfrag(&sPl[fOff]);       // [rho_r^T|rho_i^T]
      short8 Bh = (fq >= 2) ? negbf8(Ph) : Ph;                       // B = [rho_r; -rho_i]
      short8 Bl = (fq >= 2) ? negbf8(Pl) : Pl;
      mAcc = mm3(Ah, Al, Bh, Bl, zero);                              // Mr[4fq+q][fm]
      short8 Gth = (fq >= 2) ? negbf8(Ah) : Ah;                      // B-frag of [Gr^T; -Gi^T]
      short8 Gtl = (fq >= 2) ? negbf8(Al) : Al;
      mtAcc = mm3b(Ph, Pl, Gth, Gtl, zero);                          // Mr^T[4fq+q][fm]
    } else {
      // ---- Mi and Mi^T in registers (R3-verified) ----
      short8 Ah = ldfrag(&sGh[fOff]), Al = ldfrag(&sGl[fOff]);
      short8 Ph = ldfrag(&sPh[fOffS]), Pl = ldfrag(&sPl[fOffS]);     // [rho_i^T|rho_r^T]
      mAcc = mm3(Ah, Al, Ph, Pl, zero);                              // Mi[4fq+q][fm]
      mtAcc = mm3b(Ph, Pl, Ah, Al, zero);                            // Mi^T[4fq+q][fm]
    }

    __syncthreads();   // B2: sJ visible

    if (wv >= 4) {
      // ---- update: read J partials (slot copy), tree-sum, Euler, pack, write rho ----
      const float* sJ = (wv == 4) ? &sJr[0][0] : &sJi[0][0];
      f32x4 a0 = *(const f32x4*)&sJ[0*256 + ln*4];
      f32x4 a1 = *(const f32x4*)&sJ[1*256 + ln*4];
      f32x4 a2 = *(const f32x4*)&sJ[2*256 + ln*4];
      f32x4 a3 = *(const f32x4*)&sJ[3*256 + ln*4];
      short4v HH, LL;
      f32x4 rv;
      if (wv == 4) {
        #pragma unroll
        for (int q = 0; q < 4; ++q) {
          rm[q] += DTF * (mAcc[q] + mtAcc[q] + ((a0[q] + a1[q]) + (a2[q] + a3[q])));
          rv[q] = rm[q];
        }
        pack4(rv, HH, LL);
        *(short4v*)&sPh[fm*BST + row0] = HH;
        *(short4v*)&sPl[fm*BST + row0] = LL;
        if ((unsigned)(fm - row0) < 4u) sPops[t*DIM + fm] = rm[fm - row0];
      } else {
        #pragma unroll
        for (int q = 0; q < 4; ++q) {
          // Ji^T = -Ji at own element -> subtract; -Mi^T from mtAcc
          rm[q] += DTF * (mAcc[q] - mtAcc[q] - ((a0[q] + a1[q]) + (a2[q] + a3[q])));
          rv[q] = rm[q];
        }
        pack4(rv, HH, LL);
        *(short4v*)&sPh[fm*BST + 16 + row0] = HH;
        *(short4v*)&sPl[fm*BST + 16 + row0] = LL;
      }
    } else if (wv == 0) {
      // ---- G(t+1) rebuild on the idle k0 slot; write frag tile to LDS ----
      const int tn = (t + 1 < NTS) ? (t + 1) : t;
      f32x4 uv = *(const f32x4*)&sU[tn][0];
      float gv[8];
      #pragma unroll
      for (int q = 0; q < 8; ++q)
        gv[q] = G0v[q] + uv[0]*Gcv[0][q] + uv[1]*Gcv[1][q] + uv[2]*Gcv[2][q] + uv[3]*Gcv[3][q];
      short8 Gh_, Gl_;
      pack8(gv, Gh_, Gl_);
      *(short8*)&sGh[fm*BST + fq*8] = Gh_;
      *(short8*)&sGl[fm*BST + fq*8] = Gl_;
    }
    // wv1-3: idle in phase 2
  }

  // ---- final coalesced pops flush (float4), 384-thread strided ----
  __syncthreads();
  for (int i4 = tid; i4 < NTS*DIM/4; i4 += 384) {
    int idx = i4 * 4;                            // idx = t*16 + d, d 4-aligned
    int tt = idx >> 4, dd = idx & 15;
    *(float4*)&g_out[tt*(BATCH*DIM) + b*DIM + dd] = *(const float4*)&sPops[idx];
  }
}

extern "C" void kernel_launch(void* const* d_in, const int* in_sizes, int n_in,
                              void* d_out, int out_size, void* d_ws, size_t ws_size,
                              hipStream_t stream) {
  (void)out_size; (void)d_ws; (void)ws_size;
  const void *P, *H0r, *H0i, *Hcr, *Hci, *Lr, *Li, *R0r, *R0i;
  int idx64 = -1;
  for (int q = 0; q < n_in; ++q) if (in_sizes[q] == 64) idx64 = q;
  if (idx64 == 6) {   // alphabetical fallback
    H0i = d_in[0]; H0r = d_in[1];
    Hci = d_in[2]; Hcr = d_in[3];
    Li  = d_in[4]; Lr  = d_in[5];
    P   = d_in[6];
    R0i = d_in[7]; R0r = d_in[8];
  } else {            // documented setup_inputs() dict order (R4-verified)
    P   = d_in[0];
    H0r = d_in[1]; H0i = d_in[2];
    Hcr = d_in[3]; Hci = d_in[4];
    Lr  = d_in[5]; Li  = d_in[6];
    R0r = d_in[7]; R0i = d_in[8];
  }
  lindblad_evolve<<<dim3(BATCH), dim3(384), 0, stream>>>(
      P, H0r, H0i, Hcr, Hci, Lr, Li, R0r, R0i, (float*)d_out);
}